// Round 12
// baseline (52.930 us; speedup 1.0000x reference)
//
#include <hip/hip_runtime.h>

#define BATCH   2048
#define IN_DIM  16384
#define OUT_DIM 16384
#define NGATES  16

typedef float    f32x4 __attribute__((ext_vector_type(4)));
typedef _Float16 f16x4 __attribute__((ext_vector_type(4)));
typedef _Float16 f16x8 __attribute__((ext_vector_type(8)));

// COEFF[16][4] from the reference, hard-coded.
__constant__ float c_coeff[NGATES][4] = {
    {0, 0, 0, 0},  {0, 0, 0, 1},  {0, 1, 0, -1}, {0, 1, 0, 0},
    {0, 0, 1, -1}, {0, 0, 1, 0},  {0, 1, 1, -2}, {0, 1, 1, -1},
    {1, -1, -1, 1},{1, -1, -1, 2},{1, 0, -1, 0}, {1, 0, -1, 1},
    {1, -1, 0, 0}, {1, -1, 0, 1}, {1, 0, 0, -1}, {1, 0, 0, 0}
};

// Kernel 1: per output column j, fold softmax(weights[j,:]) @ COEFF into
// W[j] stored as f16x4 (8 B), and pack gather indices into one uint32.
__global__ __launch_bounds__(256) void prep_kernel(
    const float* __restrict__ weights,
    const int*   __restrict__ idx_a,
    const int*   __restrict__ idx_b,
    f16x4*       __restrict__ Wh,
    unsigned*    __restrict__ Ipk)
{
    int j = blockIdx.x * blockDim.x + threadIdx.x;
    if (j >= OUT_DIM) return;

    const float4* wrow = reinterpret_cast<const float4*>(weights + (size_t)j * NGATES);
    float v[NGATES];
    float4 q0 = wrow[0], q1 = wrow[1], q2 = wrow[2], q3 = wrow[3];
    v[0]=q0.x; v[1]=q0.y; v[2]=q0.z; v[3]=q0.w;
    v[4]=q1.x; v[5]=q1.y; v[6]=q1.z; v[7]=q1.w;
    v[8]=q2.x; v[9]=q2.y; v[10]=q2.z; v[11]=q2.w;
    v[12]=q3.x; v[13]=q3.y; v[14]=q3.z; v[15]=q3.w;

    float m = v[0];
#pragma unroll
    for (int g = 1; g < NGATES; ++g) m = fmaxf(m, v[g]);
    float s = 0.f;
#pragma unroll
    for (int g = 0; g < NGATES; ++g) { v[g] = expf(v[g] - m); s += v[g]; }
    float inv = 1.0f / s;

    float c0 = 0.f, c1 = 0.f, c2 = 0.f, c3 = 0.f;
#pragma unroll
    for (int g = 0; g < NGATES; ++g) {
        c0 += v[g] * c_coeff[g][0];
        c1 += v[g] * c_coeff[g][1];
        c2 += v[g] * c_coeff[g][2];
        c3 += v[g] * c_coeff[g][3];
    }
    f16x4 h;
    h.x = (_Float16)(c0 * inv); h.y = (_Float16)(c1 * inv);
    h.z = (_Float16)(c2 * inv); h.w = (_Float16)(c3 * inv);
    Wh[j] = h;
    Ipk[j] = (unsigned)idx_a[j] | ((unsigned)idx_b[j] << 16);   // both < 16384
}

// Kernel 2: 2048 blocks x 1024 threads, 1 row/block, 64 KB f32 LDS row ->
// 2 blocks/CU x 16 waves = 32 waves/CU (FULL wave cap). Stage is zero-VGPR
// async DMA (global_load_lds 16 B x4): 16 loads in flight per wave with no
// register cost -> no serial chain (R2's famine) and no spill (R3/R7).
// __syncthreads() drains vmcnt (incl. LDS-DMA) per compiler barrier
// semantics. f32 LDS -> gathers need no cvt. Depth-1 idx/W prefetch (R6).
__global__ __launch_bounds__(1024, 8) void logic_row_kernel(
    const float* __restrict__ x,
    const f16x8* __restrict__ Wh8,
    const uint4* __restrict__ Ipk4,
    float*       __restrict__ out)
{
    __shared__ float rowf[IN_DIM];   // 64 KB
    const int tid = threadIdx.x;
    const int i   = blockIdx.x;

    // --- Stage: 4 x 16 B async DMA per thread, zero VGPRs ---
    const float* xrow = x + (size_t)i * IN_DIM;
#pragma unroll
    for (int kk = 0; kk < 4; ++kk) {
        __builtin_amdgcn_global_load_lds(
            (const __attribute__((address_space(1))) void*)(xrow + tid * 4 + kk * 4096),
            (__attribute__((address_space(3))) void*)(rowf + tid * 4 + kk * 4096),
            16, 0, 0);
    }

    // Prefetch group 0's idx/W while the DMA streams.
    uint4 qc = Ipk4[tid];
    f16x8 wa = Wh8[(size_t)tid * 2];
    f16x8 wb = Wh8[(size_t)tid * 2 + 1];

    __syncthreads();   // drains vmcnt(0) incl. LDS-DMA; row visible

    f32x4* o4 = reinterpret_cast<f32x4*>(out + (size_t)i * OUT_DIM);

#pragma unroll
    for (int k = 0; k < OUT_DIM / 4 / 1024; ++k) {    // 4 groups of 4 outputs
        // Depth-1 prefetch of next group's row-invariant data.
        uint4 qn;  f16x8 wan, wbn;
        if (k + 1 < OUT_DIM / 4 / 1024) {
            const int j4n = tid + (k + 1) * 1024;
            qn  = Ipk4[j4n];
            wan = Wh8[(size_t)j4n * 2];
            wbn = Wh8[(size_t)j4n * 2 + 1];
        }

        // f32 gathers straight from LDS (no cvt).
        float a0 = rowf[qc.x & 0xFFFFu], b0 = rowf[qc.x >> 16];
        float a1 = rowf[qc.y & 0xFFFFu], b1 = rowf[qc.y >> 16];
        float a2 = rowf[qc.z & 0xFFFFu], b2 = rowf[qc.z >> 16];
        float a3 = rowf[qc.w & 0xFFFFu], b3 = rowf[qc.w >> 16];

        f32x4 res;
        res.x = (float)wa[0] + (float)wa[1] * a0 + (float)wa[2] * b0 + (float)wa[3] * (a0 * b0);
        res.y = (float)wa[4] + (float)wa[5] * a1 + (float)wa[6] * b1 + (float)wa[7] * (a1 * b1);
        res.z = (float)wb[0] + (float)wb[1] * a2 + (float)wb[2] * b2 + (float)wb[3] * (a2 * b2);
        res.w = (float)wb[4] + (float)wb[5] * a3 + (float)wb[6] * b3 + (float)wb[7] * (a3 * b3);
        __builtin_nontemporal_store(res, &o4[tid + k * 1024]);

        qc = qn; wa = wan; wb = wbn;
    }
}

extern "C" void kernel_launch(void* const* d_in, const int* in_sizes, int n_in,
                              void* d_out, int out_size, void* d_ws, size_t ws_size,
                              hipStream_t stream) {
    const float* x       = (const float*)d_in[0];
    const float* weights = (const float*)d_in[1];
    const int*   idx_a   = (const int*)d_in[2];
    const int*   idx_b   = (const int*)d_in[3];
    float* out = (float*)d_out;

    // Workspace layout: Wh (OUT_DIM f16x4 = 128 KB), Ipk (OUT_DIM uint = 64 KB)
    f16x4*    Wh  = (f16x4*)d_ws;
    unsigned* Ipk = (unsigned*)((char*)d_ws + (size_t)OUT_DIM * sizeof(f16x4));

    prep_kernel<<<(OUT_DIM + 255) / 256, 256, 0, stream>>>(weights, idx_a, idx_b, Wh, Ipk);
    logic_row_kernel<<<BATCH, 1024, 0, stream>>>(x, (const f16x8*)Wh, (const uint4*)Ipk, out);
}

// Round 13
// 49.001 us; speedup vs baseline: 1.0802x; 1.0802x over previous
//
#include <hip/hip_runtime.h>

#define BATCH   2048
#define IN_DIM  16384
#define OUT_DIM 16384
#define NGATES  16

typedef float    f32x4 __attribute__((ext_vector_type(4)));
typedef _Float16 f16x4 __attribute__((ext_vector_type(4)));
typedef _Float16 f16x8 __attribute__((ext_vector_type(8)));

// COEFF[16][4] from the reference, hard-coded.
__constant__ float c_coeff[NGATES][4] = {
    {0, 0, 0, 0},  {0, 0, 0, 1},  {0, 1, 0, -1}, {0, 1, 0, 0},
    {0, 0, 1, -1}, {0, 0, 1, 0},  {0, 1, 1, -2}, {0, 1, 1, -1},
    {1, -1, -1, 1},{1, -1, -1, 2},{1, 0, -1, 0}, {1, 0, -1, 1},
    {1, -1, 0, 0}, {1, -1, 0, 1}, {1, 0, 0, -1}, {1, 0, 0, 0}
};

// Kernel 1: per output column j, fold softmax(weights[j,:]) @ COEFF into
// W[j] stored as f16x4 (8 B), and pack gather indices into one uint32.
__global__ __launch_bounds__(256) void prep_kernel(
    const float* __restrict__ weights,
    const int*   __restrict__ idx_a,
    const int*   __restrict__ idx_b,
    f16x4*       __restrict__ Wh,
    unsigned*    __restrict__ Ipk)
{
    int j = blockIdx.x * blockDim.x + threadIdx.x;
    if (j >= OUT_DIM) return;

    const float4* wrow = reinterpret_cast<const float4*>(weights + (size_t)j * NGATES);
    float v[NGATES];
    float4 q0 = wrow[0], q1 = wrow[1], q2 = wrow[2], q3 = wrow[3];
    v[0]=q0.x; v[1]=q0.y; v[2]=q0.z; v[3]=q0.w;
    v[4]=q1.x; v[5]=q1.y; v[6]=q1.z; v[7]=q1.w;
    v[8]=q2.x; v[9]=q2.y; v[10]=q2.z; v[11]=q2.w;
    v[12]=q3.x; v[13]=q3.y; v[14]=q3.z; v[15]=q3.w;

    float m = v[0];
#pragma unroll
    for (int g = 1; g < NGATES; ++g) m = fmaxf(m, v[g]);
    float s = 0.f;
#pragma unroll
    for (int g = 0; g < NGATES; ++g) { v[g] = expf(v[g] - m); s += v[g]; }
    float inv = 1.0f / s;

    float c0 = 0.f, c1 = 0.f, c2 = 0.f, c3 = 0.f;
#pragma unroll
    for (int g = 0; g < NGATES; ++g) {
        c0 += v[g] * c_coeff[g][0];
        c1 += v[g] * c_coeff[g][1];
        c2 += v[g] * c_coeff[g][2];
        c3 += v[g] * c_coeff[g][3];
    }
    f16x4 h;
    h.x = (_Float16)(c0 * inv); h.y = (_Float16)(c1 * inv);
    h.z = (_Float16)(c2 * inv); h.w = (_Float16)(c3 * inv);
    Wh[j] = h;
    Ipk[j] = (unsigned)idx_a[j] | ((unsigned)idx_b[j] << 16);   // both < 16384
}

// Kernel 2 (R6, best = 49.3 us): 2048 blocks x 512 threads, 1 row/block.
// x row staged in LDS as f16 (32 KB) -> 4 blocks/CU resident (32 waves =
// full wave cap), so the stage+barrier phase of one block hides under the
// compute of three others — inter-block TLP is the only overlap mechanism
// that costs neither VGPRs (R3/R7/R9 spills) nor occupancy (R8/R10/R11).
// Per thread: 32 outputs in a depth-1 software-pipelined loop (prefetch next
// idx/W during current gather+compute). launch_bounds(512,8) caps VGPR at 64.
__global__ __launch_bounds__(512, 8) void logic_row_kernel(
    const float* __restrict__ x,
    const f16x8* __restrict__ Wh8,
    const uint4* __restrict__ Ipk4,
    float*       __restrict__ out)
{
    __shared__ _Float16 rowh[IN_DIM];   // 32 KB
    const int tid = threadIdx.x;
    const int i   = blockIdx.x;

    // --- Stage: f32x4 coalesced load -> f16x4 -> LDS (8 B/thread/chunk) ---
    const f32x4* xr  = reinterpret_cast<const f32x4*>(x + (size_t)i * IN_DIM);
    f16x4*       rhw = reinterpret_cast<f16x4*>(rowh);
#pragma unroll
    for (int k = 0; k < IN_DIM / 4 / 512; ++k) {      // 8 chunks
        f32x4 v = xr[tid + k * 512];
        f16x4 h;
        h.x = (_Float16)v.x; h.y = (_Float16)v.y;
        h.z = (_Float16)v.z; h.w = (_Float16)v.w;
        rhw[tid + k * 512] = h;
    }

    // Prefetch first group's idx/W before the barrier (L2 latency hides
    // under the stage drain).
    uint4 qc = Ipk4[tid];
    f16x8 wa = Wh8[(size_t)tid * 2];
    f16x8 wb = Wh8[(size_t)tid * 2 + 1];

    __syncthreads();

    f32x4* o4 = reinterpret_cast<f32x4*>(out + (size_t)i * OUT_DIM);

    for (int k = 0; k < OUT_DIM / 4 / 512; ++k) {     // 8 groups of 4 outputs
        // Prefetch next group's row-invariant data (independent of compute).
        uint4 qn;  f16x8 wan, wbn;
        if (k + 1 < OUT_DIM / 4 / 512) {
            const int j4n = tid + (k + 1) * 512;
            qn  = Ipk4[j4n];
            wan = Wh8[(size_t)j4n * 2];
            wbn = Wh8[(size_t)j4n * 2 + 1];
        }

        // Gather (8 independent ds_read_u16) + compute + NT store.
        float a0 = (float)rowh[qc.x & 0xFFFFu], b0 = (float)rowh[qc.x >> 16];
        float a1 = (float)rowh[qc.y & 0xFFFFu], b1 = (float)rowh[qc.y >> 16];
        float a2 = (float)rowh[qc.z & 0xFFFFu], b2 = (float)rowh[qc.z >> 16];
        float a3 = (float)rowh[qc.w & 0xFFFFu], b3 = (float)rowh[qc.w >> 16];

        f32x4 res;
        res.x = (float)wa[0] + (float)wa[1] * a0 + (float)wa[2] * b0 + (float)wa[3] * (a0 * b0);
        res.y = (float)wa[4] + (float)wa[5] * a1 + (float)wa[6] * b1 + (float)wa[7] * (a1 * b1);
        res.z = (float)wb[0] + (float)wb[1] * a2 + (float)wb[2] * b2 + (float)wb[3] * (a2 * b2);
        res.w = (float)wb[4] + (float)wb[5] * a3 + (float)wb[6] * b3 + (float)wb[7] * (a3 * b3);
        __builtin_nontemporal_store(res, &o4[tid + k * 512]);

        qc = qn; wa = wan; wb = wbn;
    }
}

extern "C" void kernel_launch(void* const* d_in, const int* in_sizes, int n_in,
                              void* d_out, int out_size, void* d_ws, size_t ws_size,
                              hipStream_t stream) {
    const float* x       = (const float*)d_in[0];
    const float* weights = (const float*)d_in[1];
    const int*   idx_a   = (const int*)d_in[2];
    const int*   idx_b   = (const int*)d_in[3];
    float* out = (float*)d_out;

    // Workspace layout: Wh (OUT_DIM f16x4 = 128 KB), Ipk (OUT_DIM uint = 64 KB)
    f16x4*    Wh  = (f16x4*)d_ws;
    unsigned* Ipk = (unsigned*)((char*)d_ws + (size_t)OUT_DIM * sizeof(f16x4));

    prep_kernel<<<(OUT_DIM + 255) / 256, 256, 0, stream>>>(weights, idx_a, idx_b, Wh, Ipk);
    logic_row_kernel<<<BATCH, 512, 0, stream>>>(x, (const f16x8*)Wh, (const uint4*)Ipk, out);
}